// Round 9
// baseline (342.292 us; speedup 1.0000x reference)
//
#include <hip/hip_runtime.h>
#include <math.h>

#define TOK 8192   // B*S tokens
#define HD  512    // hidden
#define NE  8      // experts
#define DFF 2048   // ffn dim

// ---------- bf16 helpers ----------
typedef __attribute__((ext_vector_type(8))) short bf16x8;
typedef __attribute__((ext_vector_type(4))) float floatx4;

__device__ inline unsigned short f2bf(float f) {
    union { float f; unsigned u; } v; v.f = f;
    unsigned r = v.u + 0x7FFFu + ((v.u >> 16) & 1u);   // round-nearest-even
    return (unsigned short)(r >> 16);
}

__device__ inline float gelu_exact(float v) {
    return 0.5f * v * (1.f + erff(v * 0.70710678118654752f));
}

// ---------- async global->LDS (16 B/lane; LDS dst = wave-uniform base + lane*16) ----------
typedef __attribute__((address_space(1))) const unsigned int glb_u32;
typedef __attribute__((address_space(3))) unsigned int lds_u32;
__device__ __forceinline__ void gload16(const unsigned short* g, unsigned short* l) {
    __builtin_amdgcn_global_load_lds((glb_u32*)g, (lds_u32*)l, 16, 0, 0);
}

// ---------------- prep kernel: gate (32 blocks) + weight transpose (4096 blocks) ----------------
// seg_token entries pack the top-k rank in bit 16: value = token | (rank<<16).
__global__ __launch_bounds__(256) void prep_kernel(
    const float* __restrict__ x, const float* __restrict__ gW, const float* __restrict__ gb,
    const float* __restrict__ W1, const float* __restrict__ W2,
    int* __restrict__ seg_count, float* __restrict__ probs_sum,
    int* __restrict__ seg_token, float* __restrict__ seg_w,
    unsigned short* __restrict__ xb,
    unsigned short* __restrict__ W1t, unsigned short* __restrict__ W2t)
{
    __shared__ __align__(16) char shraw[16896];
    int bid = blockIdx.x;
    int tid = threadIdx.x;

    if (bid >= 32) {
        // ---- transpose block: z<NE: W1 [e][HD][DFF]->W1t [e][DFF][HD]; else W2 -> W2t
        int b = bid - 32;
        float (*tile)[65] = (float(*)[65])shraw;
        int z = b >> 8, rem = b & 255;
        int xq = rem & 31, yq = rem >> 5;
        const float* src; unsigned short* dst; int C, R, cb, rb;
        if (z < NE) {
            src = W1 + (size_t)z * HD * DFF; dst = W1t + (size_t)z * HD * DFF;
            R = HD; C = DFF; cb = xq; rb = yq;
        } else {
            int e = z - NE;
            src = W2 + (size_t)e * DFF * HD; dst = W2t + (size_t)e * DFF * HD;
            R = DFF; C = HD; cb = yq; rb = xq;
        }
        int c0 = cb * 64, r0 = rb * 64;
        int tq = (tid & 15) * 4, tr4 = tid >> 4;
        #pragma unroll
        for (int p = 0; p < 4; p++) {
            int rr = tr4 + 16 * p;
            float4 v = *(const float4*)&src[(size_t)(r0 + rr) * C + c0 + tq];
            tile[rr][tq + 0] = v.x; tile[rr][tq + 1] = v.y;
            tile[rr][tq + 2] = v.z; tile[rr][tq + 3] = v.w;
        }
        __syncthreads();
        int cc = tid >> 3, cq = (tid & 7) * 8;
        #pragma unroll
        for (int p = 0; p < 2; p++) {
            int c = cc + 32 * p;
            union { unsigned short s[8]; uint4 v; } u8;
            #pragma unroll
            for (int u = 0; u < 8; u++) u8.s[u] = f2bf(tile[cq + u][c]);
            *(uint4*)&dst[(size_t)(c0 + c) * R + r0 + cq] = u8.v;
        }
        return;
    }

    // ---- gate block (fp32 exact) + fused x->bf16 conversion
    float* sW    = (float*)shraw;             // 16384 B
    float* psum  = (float*)(shraw + 16384);   // 32 B
    int*   lcount = (int*)(shraw + 16448);
    int*   lbase  = (int*)(shraw + 16512);

    for (int i = tid; i < HD * NE; i += 256) sW[i] = gW[i];
    if (tid < NE) { psum[tid] = 0.f; lcount[tid] = 0; }
    __syncthreads();

    int t = bid * 256 + tid;
    float logit[NE];
    #pragma unroll
    for (int e = 0; e < NE; e++) logit[e] = gb[e];

    const float4* xr4 = reinterpret_cast<const float4*>(x + (size_t)t * HD);
    ushort4* xbw = reinterpret_cast<ushort4*>(xb + (size_t)t * HD);
    for (int j4 = 0; j4 < HD / 4; j4++) {
        float4 xv = xr4[j4];
        int j = j4 * 4;
        ushort4 o; o.x = f2bf(xv.x); o.y = f2bf(xv.y); o.z = f2bf(xv.z); o.w = f2bf(xv.w);
        xbw[j4] = o;
        #pragma unroll
        for (int e = 0; e < NE; e++) {
            logit[e] += xv.x * sW[(j + 0) * NE + e] + xv.y * sW[(j + 1) * NE + e]
                      + xv.z * sW[(j + 2) * NE + e] + xv.w * sW[(j + 3) * NE + e];
        }
    }

    float mx = logit[0];
    #pragma unroll
    for (int e = 1; e < NE; e++) mx = fmaxf(mx, logit[e]);
    float pe[NE]; float s = 0.f;
    #pragma unroll
    for (int e = 0; e < NE; e++) { pe[e] = expf(logit[e] - mx); s += pe[e]; }
    float inv = 1.f / s;
    int l = tid & 63;
    #pragma unroll
    for (int e = 0; e < NE; e++) {          // wave-shuffle reduce, 1 LDS atomic/wave/e
        float v = pe[e] * inv;
        for (int off = 32; off; off >>= 1) v += __shfl_down(v, off);
        if (l == 0) atomicAdd(&psum[e], v);
    }

    // top-2, lowest-index tie break (matches jax.lax.top_k)
    int i0 = 0; float v0 = logit[0];
    #pragma unroll
    for (int e = 1; e < NE; e++) if (logit[e] > v0) { v0 = logit[e]; i0 = e; }
    int i1 = -1; float v1 = -3.4e38f;
    #pragma unroll
    for (int e = 0; e < NE; e++) if (e != i0 && logit[e] > v1) { v1 = logit[e]; i1 = e; }
    float e1 = expf(v1 - v0);
    float w0 = 1.f / (1.f + e1);
    float w1 = e1 / (1.f + e1);

    int r0 = atomicAdd(&lcount[i0], 1);
    int r1 = atomicAdd(&lcount[i1], 1);
    __syncthreads();
    if (tid < NE) lbase[tid] = atomicAdd(&seg_count[tid], lcount[tid]);
    __syncthreads();
    int p0 = lbase[i0] + r0;
    seg_token[i0 * TOK + p0] = t;                 // rank 0
    seg_w[i0 * TOK + p0] = w0;
    int p1 = lbase[i1] + r1;
    seg_token[i1 * TOK + p1] = t | (1 << 16);     // rank 1
    seg_w[i1 * TOK + p1] = w1;

    __syncthreads();
    if (tid < NE) atomicAdd(&probs_sum[tid], psum[tid]);
}

// ---------------- split GEMM path: BARRIER-FREE per-wave private pipeline ----------------
// Validated in R8 (gemm2 112->96.8us, MfmaUtil 15.0, conflicts 0). R8 BUG FIXED
// this round: gemm1's B staging offset double-counted nb*TN (w1e already includes
// it) -> wrong/OOB W1 rows for nb>0 tiles -> absmax 1.125. bofs now uses the
// region-local row (wn + rloc) only.
// Structure: each wave owns a PRIVATE LDS region (A 64x32 + B 64x32, x2 buffers
// = 16KB/wave; block = 64KB, 2 blocks/CU), self-timed with counted vmcnt only.
// ZERO __syncthreads. Per-iter: vmcnt(8) [L(k) landed; L(k+1) in flight] ->
// ds_read 8 frags -> lgkmcnt(0) -> issue L(k+2) into buf just read -> 16 MFMA.
#define TM  128
#define TN  128
#define BK  32

// LDS layout (ushort idx): wave w: base w*8192; buf b: +b*4096; A at +0, B at +2048.
#define GEMM_BODY(NITV, SRC_A, SRC_B) \
    const int NIT = (NITV); \
    int rbuf = 0; \
    for (int k = 0; k < NIT; ++k) { \
        if (k + 1 < NIT) asm volatile("s_waitcnt vmcnt(8)" ::: "memory"); \
        else             asm volatile("s_waitcnt vmcnt(0)" ::: "memory"); \
        const unsigned short* A = &smem[w * 8192 + rbuf * 4096]; \
        const unsigned short* B = A + 2048; \
        bf16x8 a[4], b[4]; \
        _Pragma("unroll") \
        for (int i = 0; i < 4; i++) a[i] = *(const bf16x8*)&A[(16 * i + lr) * BK + rsw]; \
        _Pragma("unroll") \
        for (int j = 0; j < 4; j++) b[j] = *(const bf16x8*)&B[(16 * j + lr) * BK + rsw]; \
        asm volatile("s_waitcnt lgkmcnt(0)" ::: "memory"); \
        if (k + 2 < NIT) { \
            int ko = (k + 2) * BK; \
            unsigned short* da = &smem[w * 8192 + rbuf * 4096]; \
            _Pragma("unroll") \
            for (int s = 0; s < 4; s++) { \
                gload16(SRC_A + aofs[s] + ko, da + s * 512); \
                gload16(SRC_B + bofs[s] + ko, da + 2048 + s * 512); \
            } \
        } \
        __builtin_amdgcn_s_setprio(1); \
        _Pragma("unroll") \
        for (int i = 0; i < 4; i++) \
            _Pragma("unroll") \
            for (int j = 0; j < 4; j++) \
                acc[i][j] = __builtin_amdgcn_mfma_f32_16x16x32_bf16(a[i], b[j], acc[i][j], 0, 0, 0); \
        __builtin_amdgcn_s_setprio(0); \
        rbuf ^= 1; \
    }

// GEMM1: hbuf[row, n] = gelu( xb[seg_token[e][row], :] @ W1t[e][n, :] + b1[e][n] )
__global__ __launch_bounds__(256) void gemm1_kernel(
    const unsigned short* __restrict__ xb,
    const unsigned short* __restrict__ W1t,   // [E][DFF][HD] n-major
    const float* __restrict__ bias1,
    const int* __restrict__ seg_count, const float* __restrict__ probs_sum,
    const int* __restrict__ seg_token,
    unsigned short* __restrict__ hbuf,        // [rows][DFF]
    float* __restrict__ out_tail)
{
    int bid = blockIdx.x;
    int tid = threadIdx.x;

    if (bid == 0) {           // folded finalize
        if (tid < NE) out_tail[1 + tid] = (float)seg_count[tid];
        else if (tid == 64) {
            float s = 0.f;
            #pragma unroll
            for (int e2 = 0; e2 < NE; e2++) {
                float p = probs_sum[e2] * (1.f / (float)TOK);
                s += p * p;
            }
            out_tail[0] = s * (float)NE;
        }
    }

    int e  = bid & 7;                          // low bits -> XCD affinity
    int r2 = bid >> 3;
    int nb = r2 & 15;                          // DFF/TN = 16
    int mb = r2 >> 4;                          // 0..63
    int cnt = seg_count[e];
    if (mb * TM >= cnt) return;

    int off_e = 0;
    #pragma unroll
    for (int ee = 0; ee < NE; ee++) if (ee < e) off_e += (seg_count[ee] + 127) & ~127;
    int hb = off_e + mb * TM;

    __shared__ __align__(16) unsigned short smem[32768];   // 65536 B: 4 waves x 16KB

    int w = tid >> 6, l = tid & 63;
    int lr = l & 15, crow = (l >> 4) * 4;
    int wm = (w & 1) * 64, wn = (w >> 1) * 64;
    int rsw = ((l >> 4) ^ ((lr >> 1) & 3)) * 8;       // swizzled frag read chunk
    const unsigned short* w1e = W1t + (size_t)e * DFF * HD + (size_t)(nb * TN) * HD;

    // per-lane staging addresses: lane covers region-row s*16+(l>>2), global chunk
    // (l&3)^((row>>1)&3) = (l&3)^((l>>3)&3). tok read per-lane from global (L2-hot).
    unsigned csrc = (unsigned)(((l & 3) ^ ((l >> 3) & 3)) * 8);
    unsigned aofs[4], bofs[4];
    #pragma unroll
    for (int s = 0; s < 4; s++) {
        int rloc = s * 16 + (l >> 2);
        int gi = mb * TM + wm + rloc;
        int tok = seg_token[e * TOK + ((gi < cnt) ? gi : 0)] & 0xFFFF;
        aofs[s] = (unsigned)tok * HD + csrc;
        bofs[s] = (unsigned)((wn + rloc) * HD) + csrc;   // R8 BUG FIX: w1e already
                                                         // includes nb*TN*HD
    }

    floatx4 acc[4][4];
    #pragma unroll
    for (int i = 0; i < 4; i++)
        #pragma unroll
        for (int j = 0; j < 4; j++) acc[i][j] = (floatx4){0.f, 0.f, 0.f, 0.f};

    // prologue: L(0)->buf0, L(1)->buf1 (16 outstanding)
    #pragma unroll
    for (int p = 0; p < 2; p++) {
        unsigned short* da = &smem[w * 8192 + p * 4096];
        #pragma unroll
        for (int s = 0; s < 4; s++) {
            gload16(xb  + aofs[s] + p * BK, da + s * 512);
            gload16(w1e + bofs[s] + p * BK, da + 2048 + s * 512);
        }
    }

    GEMM_BODY(HD / BK, xb, w1e)

    // epilogue: +b1, gelu, bf16 -> wave-private LDS scratch (LD 72) -> 16B stores.
    // scratch = this wave's own 16KB region; no cross-wave access -> no barrier.
    unsigned short* scr = &smem[w * 8192];
    #pragma unroll
    for (int j = 0; j < 4; j++) {
        float b1v = bias1[e * DFF + nb * TN + wn + 16 * j + lr];
        #pragma unroll
        for (int i = 0; i < 4; i++)
            #pragma unroll
            for (int rr = 0; rr < 4; rr++)
                scr[(16 * i + crow + rr) * 72 + 16 * j + lr] = f2bf(gelu_exact(acc[i][j][rr] + b1v));
    }
    int lh = l >> 3, ll = l & 7;
    #pragma unroll
    for (int k = 0; k < 8; k++) {
        uint4 v = *(const uint4*)&scr[(8 * k + lh) * 72 + ll * 8];
        int grow = hb + wm + 8 * k + lh;
        *(uint4*)&hbuf[(size_t)grow * DFF + nb * TN + wn + ll * 8] = v;
    }
}

// GEMM2: partial[t][rank] = seg_w * (hbuf[row,:] @ W2t[e][n,:] + b2[e][n])  (fast path)
//        or atomicAdd into out (mid path, use_pout=0).
__global__ __launch_bounds__(256) void gemm2_kernel(
    const unsigned short* __restrict__ hbuf,
    const unsigned short* __restrict__ W2t,   // [E][HD][DFF] n-major
    const float* __restrict__ b2,
    const int* __restrict__ seg_count, const int* __restrict__ seg_token,
    const float* __restrict__ seg_w,
    float* __restrict__ pout,                 // [TOK][2][HD] fp32 (fast path)
    float* __restrict__ out,                  // (mid path)
    int use_pout)
{
    int bid = blockIdx.x;
    int tid = threadIdx.x;
    int e  = bid & 7;
    int r2 = bid >> 3;
    int nb = r2 & 3;                           // HD/TN = 4
    int mb = r2 >> 2;                          // 0..63
    int cnt = seg_count[e];
    if (mb * TM >= cnt) return;
    int off_e = 0;
    #pragma unroll
    for (int ee = 0; ee < NE; ee++) if (ee < e) off_e += (seg_count[ee] + 127) & ~127;
    int hb = off_e + mb * TM;

    __shared__ __align__(16) unsigned short smem[32768];   // 65536 B

    int w = tid >> 6, l = tid & 63;
    int lr = l & 15, crow = (l >> 4) * 4;
    int wm = (w & 1) * 64, wn = (w >> 1) * 64;
    int rsw = ((l >> 4) ^ ((lr >> 1) & 3)) * 8;
    const unsigned short* w2e = W2t + (size_t)e * HD * DFF + (size_t)(nb * TN) * DFF;

    unsigned csrc = (unsigned)(((l & 3) ^ ((l >> 3) & 3)) * 8);
    unsigned aofs[4], bofs[4];
    #pragma unroll
    for (int s = 0; s < 4; s++) {
        int rloc = s * 16 + (l >> 2);
        aofs[s] = (unsigned)((hb + wm + rloc) * DFF) + csrc;
        bofs[s] = (unsigned)((wn + rloc) * DFF) + csrc;
    }

    floatx4 acc[4][4];
    #pragma unroll
    for (int i = 0; i < 4; i++)
        #pragma unroll
        for (int j = 0; j < 4; j++) acc[i][j] = (floatx4){0.f, 0.f, 0.f, 0.f};

    #pragma unroll
    for (int p = 0; p < 2; p++) {
        unsigned short* da = &smem[w * 8192 + p * 4096];
        #pragma unroll
        for (int s = 0; s < 4; s++) {
            gload16(hbuf + aofs[s] + p * BK, da + s * 512);
            gload16(w2e  + bofs[s] + p * BK, da + 2048 + s * 512);
        }
    }

    GEMM_BODY(DFF / BK, hbuf, w2e)

    // epilogue: per-lane tok/rank/wgt loads from global (L2-hot, once)
    int   raws[4][4];
    float wgts[4][4];
    #pragma unroll
    for (int i = 0; i < 4; i++)
        #pragma unroll
        for (int rr = 0; rr < 4; rr++) {
            int gi = mb * TM + wm + 16 * i + crow + rr;
            int idx = e * TOK + ((gi < cnt) ? gi : 0);
            raws[i][rr] = seg_token[idx];
            wgts[i][rr] = (gi < cnt) ? seg_w[idx] : 0.f;
        }

    if (use_pout) {
        #pragma unroll
        for (int j = 0; j < 4; j++) {
            int n = nb * TN + wn + 16 * j + lr;
            float b2v = b2[e * HD + n];
            #pragma unroll
            for (int i = 0; i < 4; i++)
                #pragma unroll
                for (int rr = 0; rr < 4; rr++) {
                    int gi = mb * TM + wm + 16 * i + crow + rr;
                    if (gi < cnt)
                        pout[((size_t)(raws[i][rr] & 0xFFFF) * 2 + (raws[i][rr] >> 16)) * HD + n] =
                            (acc[i][j][rr] + b2v) * wgts[i][rr];
                }
        }
    } else {
        #pragma unroll
        for (int j = 0; j < 4; j++) {
            int n = nb * TN + wn + 16 * j + lr;
            float b2v = b2[e * HD + n];
            #pragma unroll
            for (int i = 0; i < 4; i++)
                #pragma unroll
                for (int rr = 0; rr < 4; rr++)
                    atomicAdd(&out[(size_t)(raws[i][rr] & 0xFFFF) * HD + n],
                              (acc[i][j][rr] + b2v) * wgts[i][rr]);
        }
    }
}

// combine: out[t] = pout[t][0] + pout[t][1]  (weights & biases already folded)
__global__ __launch_bounds__(256) void combine_kernel(
    const float* __restrict__ pout, float* __restrict__ out)
{
    int idx = blockIdx.x * 256 + threadIdx.x;          // TOK*HD/4 float4s
    int t = idx >> 7;                                  // 128 float4 per token
    int c4 = idx & 127;
    const float4* p = (const float4*)pout;
    float4 a = p[((size_t)t * 2 + 0) * 128 + c4];
    float4 b = p[((size_t)t * 2 + 1) * 128 + c4];
    float4 r; r.x = a.x + b.x; r.y = a.y + b.y; r.z = a.z + b.z; r.w = a.w + b.w;
    ((float4*)out)[idx] = r;
}

// ---------------- fused fallback (ws too small): full-unroll ----------------
#define BMT 64
#define FK  64
#define XS_LD 520
#define HS_LD 72

__global__ __launch_bounds__(256, 2) void ffn_fused_fallback(
    const unsigned short* __restrict__ xb,
    const unsigned short* __restrict__ W1t, const float* __restrict__ b1,
    const unsigned short* __restrict__ W2t, const float* __restrict__ b2,
    const int* __restrict__ seg_count, const int* __restrict__ seg_token,
    const float* __restrict__ seg_w, float* __restrict__ out)
{
    int bid = blockIdx.x;
    int e = bid & 7;
    int g = bid >> 3;
    int cnt = seg_count[e];
    int n0 = g * BMT;
    if (n0 >= cnt) return;
    int rows = min(BMT, cnt - n0);

    __shared__ unsigned short xs[BMT * XS_LD];
    __shared__ unsigned short hs[BMT * HS_LD];
    __shared__ int   tok_s[BMT];
    __shared__ float wgt_s[BMT];

    int tid = threadIdx.x;
    if (tid < BMT) {
        int idx = (tid < rows) ? (n0 + tid) : n0;
        tok_s[tid] = seg_token[e * TOK + idx] & 0xFFFF;
        wgt_s[tid] = (tid < rows) ? seg_w[e * TOK + idx] : 0.f;
    }
    __syncthreads();
    {
        int r = tid >> 2, q = tid & 3;
        const uint4* src = (const uint4*)(xb + (size_t)tok_s[r] * HD) + q * 16;
        uint4* dst = (uint4*)&xs[(size_t)r * XS_LD + q * 128];
        #pragma unroll
        for (int i = 0; i < 16; i++) dst[i] = src[i];
    }
    __syncthreads();

    int w = tid >> 6, l = tid & 63;
    int lr = l & 15, lk = (l >> 4) * 8, crow = (l >> 4) * 4;

    const unsigned short* w1e = W1t + (size_t)e * DFF * HD;
    const unsigned short* w2e = W2t + (size_t)e * HD * DFF;

    floatx4 acc2[4][8];
    #pragma unroll
    for (int i = 0; i < 4; i++)
        #pragma unroll
        for (int j = 0; j < 8; j++) acc2[i][j] = (floatx4){0.f, 0.f, 0.f, 0.f};

    for (int fc = 0; fc < DFF; fc += FK) {
        floatx4 acc1[4];
        #pragma unroll
        for (int t = 0; t < 4; t++) acc1[t] = (floatx4){0.f, 0.f, 0.f, 0.f};
        const unsigned short* w1c = w1e + (size_t)fc * HD;
        for (int ks = 0; ks < HD; ks += 32) {
            bf16x8 a = *(const bf16x8*)&xs[(16 * w + lr) * XS_LD + ks + lk];
            #pragma unroll
            for (int t = 0; t < 4; t++) {
                bf16x8 b = *(const bf16x8*)(w1c + (size_t)(16 * t + lr) * HD + ks + lk);
                acc1[t] = __builtin_amdgcn_mfma_f32_16x16x32_bf16(a, b, acc1[t], 0, 0, 0);
            }
        }
        __syncthreads();
        #pragma unroll
        for (int t = 0; t < 4; t++) {
            float b1v = b1[e * DFF + fc + 16 * t + lr];
            #pragma unroll
            for (int r = 0; r < 4; r++)
                hs[(16 * w + crow + r) * HS_LD + 16 * t + lr] = f2bf(gelu_exact(acc1[t][r] + b1v));
        }
        __syncthreads();
        #pragma unroll
        for (int ks = 0; ks < FK; ks += 32) {
            bf16x8 af[4];
            #pragma unroll
            for (int i = 0; i < 4; i++) af[i] = *(const bf16x8*)&hs[(16 * i + lr) * HS_LD + ks + lk];
            #pragma unroll
            for (int j = 0; j < 8; j++) {      // FULL unroll (rule #20)
                bf16x8 b = *(const bf16x8*)(w2e + (size_t)(128 * w + 16 * j + lr) * DFF + fc + ks + lk);
                #pragma unroll
                for (int i = 0; i < 4; i++)
                    acc2[i][j] = __builtin_amdgcn_mfma_f32_16x16x32_bf16(af[i], b, acc2[i][j], 0, 0, 0);
            }
        }
    }
    #pragma unroll
    for (int j = 0; j < 8; j++) {
        int n = 128 * w + 16 * j + lr;
        float b2v = b2[e * HD + n];
        #pragma unroll
        for (int i = 0; i < 4; i++)
            #pragma unroll
            for (int r = 0; r < 4; r++) {
                int m = 16 * i + crow + r;
                atomicAdd(&out[(size_t)tok_s[m] * HD + n], (acc2[i][j][r] + b2v) * wgt_s[m]);
            }
    }
}

// tiny finalize for fallback path
__global__ void finalize_kernel(const int* __restrict__ seg_count,
                                const float* __restrict__ probs_sum,
                                float* __restrict__ out_tail)
{
    int tid = threadIdx.x;
    if (tid < NE) out_tail[1 + tid] = (float)seg_count[tid];
    if (tid == 0) {
        float s = 0.f;
        #pragma unroll
        for (int e = 0; e < NE; e++) {
            float p = probs_sum[e] * (1.f / (float)TOK);
            s += p * p;
        }
        out_tail[0] = s * (float)NE;
    }
}

extern "C" void kernel_launch(void* const* d_in, const int* in_sizes, int n_in,
                              void* d_out, int out_size, void* d_ws, size_t ws_size,
                              hipStream_t stream)
{
    const float* x  = (const float*)d_in[0];
    const float* gW = (const float*)d_in[1];
    const float* gb = (const float*)d_in[2];
    const float* W1 = (const float*)d_in[3];
    const float* b1 = (const float*)d_in[4];
    const float* W2 = (const float*)d_in[5];
    const float* b2 = (const float*)d_in[6];
    float* out = (float*)d_out;

    char* ws = (char*)d_ws;
    int*   seg_count = (int*)ws;                          // 32 B
    float* probs_sum = (float*)(ws + 32);                 // 32 B
    int*   seg_token = (int*)(ws + 4096);                 // 256 KiB
    float* seg_w     = (float*)(ws + 4096 + (size_t)NE * TOK * 4);   // 256 KiB

    const size_t HBUF_BYTES = (size_t)17408 * DFF * 2;    // 71.3 MB

    // ---- fast layout: pout overlays xb+W1t (dead during gemm2) ----
    const size_t F_POUT = 0xA0000;                        // 655,360 (after seg arrays)
    const size_t F_XB   = (1u  << 20);                    // inside pout region
    const size_t F_W1T  = (9u  << 20);                    // inside pout region
    const size_t F_W2T  = F_POUT + (size_t)TOK * 2 * HD * 4;   // 655,360 + 32 MiB
    const size_t F_HBUF = F_W2T + ((size_t)NE * DFF * HD * 2); // + 16 MiB
    const size_t WS_FAST = F_HBUF + HBUF_BYTES;           // ~122.3 MB

    // ---- mid layout (atomic epilogue) ----
    const size_t M_XB   = (1u  << 20);
    const size_t M_W1T  = (16u << 20);
    const size_t M_W2T  = (32u << 20);
    const size_t M_HBUF = (48u << 20);
    const size_t WS_MID = M_HBUF + HBUF_BYTES;            // ~121.6 MB

    hipMemsetAsync(d_ws, 0, 64, stream);

    if (ws_size >= WS_FAST) {
        unsigned short* xb   = (unsigned short*)(ws + F_XB);
        unsigned short* W1t  = (unsigned short*)(ws + F_W1T);
        unsigned short* W2t  = (unsigned short*)(ws + F_W2T);
        unsigned short* hbuf = (unsigned short*)(ws + F_HBUF);
        float*          pout = (float*)(ws + F_POUT);

        prep_kernel<<<4128, 256, 0, stream>>>(x, gW, gb, W1, W2,
                                              seg_count, probs_sum, seg_token, seg_w,
                                              xb, W1t, W2t);
        gemm1_kernel<<<NE * (DFF / TN) * 64, 256, 0, stream>>>(
            xb, W1t, b1, seg_count, probs_sum, seg_token, hbuf,
            out + (size_t)TOK * HD);
        gemm2_kernel<<<NE * (HD / TN) * 64, 256, 0, stream>>>(
            hbuf, W2t, b2, seg_count, seg_token, seg_w, pout, out, 1);
        combine_kernel<<<(TOK * HD / 4) / 256, 256, 0, stream>>>(pout, out);
    } else if (ws_size >= WS_MID) {
        unsigned short* xb   = (unsigned short*)(ws + M_XB);
        unsigned short* W1t  = (unsigned short*)(ws + M_W1T);
        unsigned short* W2t  = (unsigned short*)(ws + M_W2T);
        unsigned short* hbuf = (unsigned short*)(ws + M_HBUF);

        hipMemsetAsync(d_out, 0, (size_t)TOK * HD * sizeof(float), stream);
        prep_kernel<<<4128, 256, 0, stream>>>(x, gW, gb, W1, W2,
                                              seg_count, probs_sum, seg_token, seg_w,
                                              xb, W1t, W2t);
        gemm1_kernel<<<NE * (DFF / TN) * 64, 256, 0, stream>>>(
            xb, W1t, b1, seg_count, probs_sum, seg_token, hbuf,
            out + (size_t)TOK * HD);
        gemm2_kernel<<<NE * (HD / TN) * 64, 256, 0, stream>>>(
            hbuf, W2t, b2, seg_count, seg_token, seg_w, (float*)ws, out, 0);
    } else {
        unsigned short* xb   = (unsigned short*)(ws + M_XB);
        unsigned short* W1t  = (unsigned short*)(ws + M_W1T);
        unsigned short* W2t  = (unsigned short*)(ws + M_W2T);

        hipMemsetAsync(d_out, 0, (size_t)TOK * HD * sizeof(float), stream);
        prep_kernel<<<4128, 256, 0, stream>>>(x, gW, gb, W1, W2,
                                              seg_count, probs_sum, seg_token, seg_w,
                                              xb, W1t, W2t);
        finalize_kernel<<<1, 64, 0, stream>>>(seg_count, probs_sum, out + (size_t)TOK * HD);
        ffn_fused_fallback<<<(TOK / BMT) * NE, 256, 0, stream>>>(
            xb, W1t, b1, W2t, b2, seg_count, seg_token, seg_w, out);
    }
}

// Round 10
// 339.671 us; speedup vs baseline: 1.0077x; 1.0077x over previous
//
#include <hip/hip_runtime.h>
#include <math.h>

#define TOK 8192   // B*S tokens
#define HD  512    // hidden
#define NE  8      // experts
#define DFF 2048   // ffn dim

// ---------- bf16 helpers ----------
typedef __attribute__((ext_vector_type(8))) short bf16x8;
typedef __attribute__((ext_vector_type(4))) float floatx4;

__device__ inline unsigned short f2bf(float f) {
    union { float f; unsigned u; } v; v.f = f;
    unsigned r = v.u + 0x7FFFu + ((v.u >> 16) & 1u);   // round-nearest-even
    return (unsigned short)(r >> 16);
}

__device__ inline float gelu_exact(float v) {
    return 0.5f * v * (1.f + erff(v * 0.70710678118654752f));
}

// ---------- async global->LDS (16 B/lane; LDS dst = wave-uniform base + lane*16) ----------
typedef __attribute__((address_space(1))) const unsigned int glb_u32;
typedef __attribute__((address_space(3))) unsigned int lds_u32;
__device__ __forceinline__ void gload16(const unsigned short* g, unsigned short* l) {
    __builtin_amdgcn_global_load_lds((glb_u32*)g, (lds_u32*)l, 16, 0, 0);
}

// ---------------- prep kernel: gate (32 blocks) + weight transpose ----------------
// seg_token entries pack the top-k rank in bit 16: value = token | (rank<<16).
// R10: fast/mid paths launch only 2080 blocks (gate + W1 transpose). The W2
// transpose (z>=NE range, bid 2080..4127) moved into gemm1's launch to overlap
// with gemm1's latency-bound execution. Fallback path still launches 4128.
__global__ __launch_bounds__(256) void prep_kernel(
    const float* __restrict__ x, const float* __restrict__ gW, const float* __restrict__ gb,
    const float* __restrict__ W1, const float* __restrict__ W2,
    int* __restrict__ seg_count, float* __restrict__ probs_sum,
    int* __restrict__ seg_token, float* __restrict__ seg_w,
    unsigned short* __restrict__ xb,
    unsigned short* __restrict__ W1t, unsigned short* __restrict__ W2t)
{
    __shared__ __align__(16) char shraw[16896];
    int bid = blockIdx.x;
    int tid = threadIdx.x;

    if (bid >= 32) {
        // ---- transpose block: z<NE: W1 [e][HD][DFF]->W1t [e][DFF][HD]; else W2 -> W2t
        int b = bid - 32;
        float (*tile)[65] = (float(*)[65])shraw;
        int z = b >> 8, rem = b & 255;
        int xq = rem & 31, yq = rem >> 5;
        const float* src; unsigned short* dst; int C, R, cb, rb;
        if (z < NE) {
            src = W1 + (size_t)z * HD * DFF; dst = W1t + (size_t)z * HD * DFF;
            R = HD; C = DFF; cb = xq; rb = yq;
        } else {
            int e = z - NE;
            src = W2 + (size_t)e * DFF * HD; dst = W2t + (size_t)e * DFF * HD;
            R = DFF; C = HD; cb = yq; rb = xq;
        }
        int c0 = cb * 64, r0 = rb * 64;
        int tq = (tid & 15) * 4, tr4 = tid >> 4;
        #pragma unroll
        for (int p = 0; p < 4; p++) {
            int rr = tr4 + 16 * p;
            float4 v = *(const float4*)&src[(size_t)(r0 + rr) * C + c0 + tq];
            tile[rr][tq + 0] = v.x; tile[rr][tq + 1] = v.y;
            tile[rr][tq + 2] = v.z; tile[rr][tq + 3] = v.w;
        }
        __syncthreads();
        int cc = tid >> 3, cq = (tid & 7) * 8;
        #pragma unroll
        for (int p = 0; p < 2; p++) {
            int c = cc + 32 * p;
            union { unsigned short s[8]; uint4 v; } u8;
            #pragma unroll
            for (int u = 0; u < 8; u++) u8.s[u] = f2bf(tile[cq + u][c]);
            *(uint4*)&dst[(size_t)(c0 + c) * R + r0 + cq] = u8.v;
        }
        return;
    }

    // ---- gate block (fp32 exact) + fused x->bf16 conversion
    float* sW    = (float*)shraw;             // 16384 B
    float* psum  = (float*)(shraw + 16384);   // 32 B
    int*   lcount = (int*)(shraw + 16448);
    int*   lbase  = (int*)(shraw + 16512);

    for (int i = tid; i < HD * NE; i += 256) sW[i] = gW[i];
    if (tid < NE) { psum[tid] = 0.f; lcount[tid] = 0; }
    __syncthreads();

    int t = bid * 256 + tid;
    float logit[NE];
    #pragma unroll
    for (int e = 0; e < NE; e++) logit[e] = gb[e];

    const float4* xr4 = reinterpret_cast<const float4*>(x + (size_t)t * HD);
    ushort4* xbw = reinterpret_cast<ushort4*>(xb + (size_t)t * HD);
    for (int j4 = 0; j4 < HD / 4; j4++) {
        float4 xv = xr4[j4];
        int j = j4 * 4;
        ushort4 o; o.x = f2bf(xv.x); o.y = f2bf(xv.y); o.z = f2bf(xv.z); o.w = f2bf(xv.w);
        xbw[j4] = o;
        #pragma unroll
        for (int e = 0; e < NE; e++) {
            logit[e] += xv.x * sW[(j + 0) * NE + e] + xv.y * sW[(j + 1) * NE + e]
                      + xv.z * sW[(j + 2) * NE + e] + xv.w * sW[(j + 3) * NE + e];
        }
    }

    float mx = logit[0];
    #pragma unroll
    for (int e = 1; e < NE; e++) mx = fmaxf(mx, logit[e]);
    float pe[NE]; float s = 0.f;
    #pragma unroll
    for (int e = 0; e < NE; e++) { pe[e] = expf(logit[e] - mx); s += pe[e]; }
    float inv = 1.f / s;
    int l = tid & 63;
    #pragma unroll
    for (int e = 0; e < NE; e++) {          // wave-shuffle reduce, 1 LDS atomic/wave/e
        float v = pe[e] * inv;
        for (int off = 32; off; off >>= 1) v += __shfl_down(v, off);
        if (l == 0) atomicAdd(&psum[e], v);
    }

    // top-2, lowest-index tie break (matches jax.lax.top_k)
    int i0 = 0; float v0 = logit[0];
    #pragma unroll
    for (int e = 1; e < NE; e++) if (logit[e] > v0) { v0 = logit[e]; i0 = e; }
    int i1 = -1; float v1 = -3.4e38f;
    #pragma unroll
    for (int e = 0; e < NE; e++) if (e != i0 && logit[e] > v1) { v1 = logit[e]; i1 = e; }
    float e1 = expf(v1 - v0);
    float w0 = 1.f / (1.f + e1);
    float w1 = e1 / (1.f + e1);

    int r0 = atomicAdd(&lcount[i0], 1);
    int r1 = atomicAdd(&lcount[i1], 1);
    __syncthreads();
    if (tid < NE) lbase[tid] = atomicAdd(&seg_count[tid], lcount[tid]);
    __syncthreads();
    int p0 = lbase[i0] + r0;
    seg_token[i0 * TOK + p0] = t;                 // rank 0
    seg_w[i0 * TOK + p0] = w0;
    int p1 = lbase[i1] + r1;
    seg_token[i1 * TOK + p1] = t | (1 << 16);     // rank 1
    seg_w[i1 * TOK + p1] = w1;

    __syncthreads();
    if (tid < NE) atomicAdd(&probs_sum[tid], psum[tid]);
}

// ---------------- split GEMM path: BARRIER-FREE per-wave private pipeline ----------------
// Validated R8/R9: gemm2 112->97us, MfmaUtil 15, conflicts 0, absmax correct.
// Each wave owns a PRIVATE LDS region (A 64x32 + B 64x32, x2 buffers = 16KB/wave;
// block = 64KB, 2 blocks/CU), self-timed with counted vmcnt only. ZERO
// __syncthreads. Per-iter: vmcnt(8) [L(k) landed; L(k+1) in flight] -> ds_read
// 8 frags -> lgkmcnt(0) -> issue L(k+2) into buf just read -> 16 MFMA.
#define TM  128
#define TN  128
#define BK  32
#define G1_GRID (NE * (DFF / TN) * 64)   // 8192

// LDS layout (ushort idx): wave w: base w*8192; buf b: +b*4096; A at +0, B at +2048.
#define GEMM_BODY(NITV, SRC_A, SRC_B) \
    const int NIT = (NITV); \
    int rbuf = 0; \
    for (int k = 0; k < NIT; ++k) { \
        if (k + 1 < NIT) asm volatile("s_waitcnt vmcnt(8)" ::: "memory"); \
        else             asm volatile("s_waitcnt vmcnt(0)" ::: "memory"); \
        const unsigned short* A = &smem[w * 8192 + rbuf * 4096]; \
        const unsigned short* B = A + 2048; \
        bf16x8 a[4], b[4]; \
        _Pragma("unroll") \
        for (int i = 0; i < 4; i++) a[i] = *(const bf16x8*)&A[(16 * i + lr) * BK + rsw]; \
        _Pragma("unroll") \
        for (int j = 0; j < 4; j++) b[j] = *(const bf16x8*)&B[(16 * j + lr) * BK + rsw]; \
        asm volatile("s_waitcnt lgkmcnt(0)" ::: "memory"); \
        if (k + 2 < NIT) { \
            int ko = (k + 2) * BK; \
            unsigned short* da = &smem[w * 8192 + rbuf * 4096]; \
            _Pragma("unroll") \
            for (int s = 0; s < 4; s++) { \
                gload16(SRC_A + aofs[s] + ko, da + s * 512); \
                gload16(SRC_B + bofs[s] + ko, da + 2048 + s * 512); \
            } \
        } \
        __builtin_amdgcn_s_setprio(1); \
        _Pragma("unroll") \
        for (int i = 0; i < 4; i++) \
            _Pragma("unroll") \
            for (int j = 0; j < 4; j++) \
                acc[i][j] = __builtin_amdgcn_mfma_f32_16x16x32_bf16(a[i], b[j], acc[i][j], 0, 0, 0); \
        __builtin_amdgcn_s_setprio(0); \
        rbuf ^= 1; \
    }

// GEMM1: hbuf[row, n] = gelu( xb[seg_token[e][row], :] @ W1t[e][n, :] + b1[e][n] )
// R10: blocks bid >= G1_GRID run the W2->W2t transpose (moved out of prep),
// overlapping W2t production with gemm1's latency-bound GEMM blocks. W2t is
// first consumed by gemm2 (next launch, stream-ordered -> coherent).
__global__ __launch_bounds__(256) void gemm1_kernel(
    const unsigned short* __restrict__ xb,
    const unsigned short* __restrict__ W1t,   // [E][DFF][HD] n-major
    const float* __restrict__ bias1,
    const int* __restrict__ seg_count, const float* __restrict__ probs_sum,
    const int* __restrict__ seg_token,
    unsigned short* __restrict__ hbuf,        // [rows][DFF]
    float* __restrict__ out_tail,
    const float* __restrict__ W2src,          // fp32 W2 (transpose source)
    unsigned short* __restrict__ W2t)         // transpose dst
{
    int bid = blockIdx.x;
    int tid = threadIdx.x;

    __shared__ __align__(16) unsigned short smem[32768];   // 65536 B: 4 waves x 16KB

    if (bid >= G1_GRID) {
        // ---- appended W2 transpose block: W2 [e][DFF][HD] -> W2t [e][HD][DFF]
        int b = bid - G1_GRID;                 // 0..2047
        float (*tile)[65] = (float(*)[65])smem;  // 16640 B of the 64KB
        int e = b >> 8, rem = b & 255;
        int xq = rem & 31, yq = rem >> 5;
        const float* src = W2src + (size_t)e * DFF * HD;
        unsigned short* dst = W2t + (size_t)e * DFF * HD;
        const int R = DFF, C = HD;
        int c0 = yq * 64, r0 = xq * 64;
        int tq = (tid & 15) * 4, tr4 = tid >> 4;
        #pragma unroll
        for (int p = 0; p < 4; p++) {
            int rr = tr4 + 16 * p;
            float4 v = *(const float4*)&src[(size_t)(r0 + rr) * C + c0 + tq];
            tile[rr][tq + 0] = v.x; tile[rr][tq + 1] = v.y;
            tile[rr][tq + 2] = v.z; tile[rr][tq + 3] = v.w;
        }
        __syncthreads();
        int cc = tid >> 3, cq = (tid & 7) * 8;
        #pragma unroll
        for (int p = 0; p < 2; p++) {
            int c = cc + 32 * p;
            union { unsigned short s[8]; uint4 v; } u8;
            #pragma unroll
            for (int u = 0; u < 8; u++) u8.s[u] = f2bf(tile[cq + u][c]);
            *(uint4*)&dst[(size_t)(c0 + c) * R + r0 + cq] = u8.v;
        }
        return;
    }

    if (bid == 0) {           // folded finalize
        if (tid < NE) out_tail[1 + tid] = (float)seg_count[tid];
        else if (tid == 64) {
            float s = 0.f;
            #pragma unroll
            for (int e2 = 0; e2 < NE; e2++) {
                float p = probs_sum[e2] * (1.f / (float)TOK);
                s += p * p;
            }
            out_tail[0] = s * (float)NE;
        }
    }

    int e  = bid & 7;                          // low bits -> XCD affinity
    int r2 = bid >> 3;
    int nb = r2 & 15;                          // DFF/TN = 16
    int mb = r2 >> 4;                          // 0..63
    int cnt = seg_count[e];
    if (mb * TM >= cnt) return;

    int off_e = 0;
    #pragma unroll
    for (int ee = 0; ee < NE; ee++) if (ee < e) off_e += (seg_count[ee] + 127) & ~127;
    int hb = off_e + mb * TM;

    int w = tid >> 6, l = tid & 63;
    int lr = l & 15, crow = (l >> 4) * 4;
    int wm = (w & 1) * 64, wn = (w >> 1) * 64;
    int rsw = ((l >> 4) ^ ((lr >> 1) & 3)) * 8;       // swizzled frag read chunk
    const unsigned short* w1e = W1t + (size_t)e * DFF * HD + (size_t)(nb * TN) * HD;

    // per-lane staging addresses: lane covers region-row s*16+(l>>2), global chunk
    // (l&3)^((row>>1)&3) = (l&3)^((l>>3)&3). tok read per-lane from global (L2-hot).
    unsigned csrc = (unsigned)(((l & 3) ^ ((l >> 3) & 3)) * 8);
    unsigned aofs[4], bofs[4];
    #pragma unroll
    for (int s = 0; s < 4; s++) {
        int rloc = s * 16 + (l >> 2);
        int gi = mb * TM + wm + rloc;
        int tok = seg_token[e * TOK + ((gi < cnt) ? gi : 0)] & 0xFFFF;
        aofs[s] = (unsigned)tok * HD + csrc;
        bofs[s] = (unsigned)((wn + rloc) * HD) + csrc;   // region-local (w1e has nb*TN*HD)
    }

    floatx4 acc[4][4];
    #pragma unroll
    for (int i = 0; i < 4; i++)
        #pragma unroll
        for (int j = 0; j < 4; j++) acc[i][j] = (floatx4){0.f, 0.f, 0.f, 0.f};

    // prologue: L(0)->buf0, L(1)->buf1 (16 outstanding)
    #pragma unroll
    for (int p = 0; p < 2; p++) {
        unsigned short* da = &smem[w * 8192 + p * 4096];
        #pragma unroll
        for (int s = 0; s < 4; s++) {
            gload16(xb  + aofs[s] + p * BK, da + s * 512);
            gload16(w1e + bofs[s] + p * BK, da + 2048 + s * 512);
        }
    }

    GEMM_BODY(HD / BK, xb, w1e)

    // epilogue: +b1, gelu, bf16 -> wave-private LDS scratch (LD 72) -> 16B stores.
    // scratch = this wave's own 16KB region; no cross-wave access -> no barrier.
    unsigned short* scr = &smem[w * 8192];
    #pragma unroll
    for (int j = 0; j < 4; j++) {
        float b1v = bias1[e * DFF + nb * TN + wn + 16 * j + lr];
        #pragma unroll
        for (int i = 0; i < 4; i++)
            #pragma unroll
            for (int rr = 0; rr < 4; rr++)
                scr[(16 * i + crow + rr) * 72 + 16 * j + lr] = f2bf(gelu_exact(acc[i][j][rr] + b1v));
    }
    int lh = l >> 3, ll = l & 7;
    #pragma unroll
    for (int k = 0; k < 8; k++) {
        uint4 v = *(const uint4*)&scr[(8 * k + lh) * 72 + ll * 8];
        int grow = hb + wm + 8 * k + lh;
        *(uint4*)&hbuf[(size_t)grow * DFF + nb * TN + wn + ll * 8] = v;
    }
}

// GEMM2: partial[t][rank] = seg_w * (hbuf[row,:] @ W2t[e][n,:] + b2[e][n])  (fast path)
//        or atomicAdd into out (mid path, use_pout=0).
__global__ __launch_bounds__(256) void gemm2_kernel(
    const unsigned short* __restrict__ hbuf,
    const unsigned short* __restrict__ W2t,   // [E][HD][DFF] n-major
    const float* __restrict__ b2,
    const int* __restrict__ seg_count, const int* __restrict__ seg_token,
    const float* __restrict__ seg_w,
    float* __restrict__ pout,                 // [TOK][2][HD] fp32 (fast path)
    float* __restrict__ out,                  // (mid path)
    int use_pout)
{
    int bid = blockIdx.x;
    int tid = threadIdx.x;
    int e  = bid & 7;
    int r2 = bid >> 3;
    int nb = r2 & 3;                           // HD/TN = 4
    int mb = r2 >> 2;                          // 0..63
    int cnt = seg_count[e];
    if (mb * TM >= cnt) return;
    int off_e = 0;
    #pragma unroll
    for (int ee = 0; ee < NE; ee++) if (ee < e) off_e += (seg_count[ee] + 127) & ~127;
    int hb = off_e + mb * TM;

    __shared__ __align__(16) unsigned short smem[32768];   // 65536 B

    int w = tid >> 6, l = tid & 63;
    int lr = l & 15, crow = (l >> 4) * 4;
    int wm = (w & 1) * 64, wn = (w >> 1) * 64;
    int rsw = ((l >> 4) ^ ((lr >> 1) & 3)) * 8;
    const unsigned short* w2e = W2t + (size_t)e * HD * DFF + (size_t)(nb * TN) * DFF;

    unsigned csrc = (unsigned)(((l & 3) ^ ((l >> 3) & 3)) * 8);
    unsigned aofs[4], bofs[4];
    #pragma unroll
    for (int s = 0; s < 4; s++) {
        int rloc = s * 16 + (l >> 2);
        aofs[s] = (unsigned)((hb + wm + rloc) * DFF) + csrc;
        bofs[s] = (unsigned)((wn + rloc) * DFF) + csrc;
    }

    floatx4 acc[4][4];
    #pragma unroll
    for (int i = 0; i < 4; i++)
        #pragma unroll
        for (int j = 0; j < 4; j++) acc[i][j] = (floatx4){0.f, 0.f, 0.f, 0.f};

    #pragma unroll
    for (int p = 0; p < 2; p++) {
        unsigned short* da = &smem[w * 8192 + p * 4096];
        #pragma unroll
        for (int s = 0; s < 4; s++) {
            gload16(hbuf + aofs[s] + p * BK, da + s * 512);
            gload16(w2e  + bofs[s] + p * BK, da + 2048 + s * 512);
        }
    }

    GEMM_BODY(DFF / BK, hbuf, w2e)

    // epilogue: per-lane tok/rank/wgt loads from global (L2-hot, once)
    int   raws[4][4];
    float wgts[4][4];
    #pragma unroll
    for (int i = 0; i < 4; i++)
        #pragma unroll
        for (int rr = 0; rr < 4; rr++) {
            int gi = mb * TM + wm + 16 * i + crow + rr;
            int idx = e * TOK + ((gi < cnt) ? gi : 0);
            raws[i][rr] = seg_token[idx];
            wgts[i][rr] = (gi < cnt) ? seg_w[idx] : 0.f;
        }

    if (use_pout) {
        #pragma unroll
        for (int j = 0; j < 4; j++) {
            int n = nb * TN + wn + 16 * j + lr;
            float b2v = b2[e * HD + n];
            #pragma unroll
            for (int i = 0; i < 4; i++)
                #pragma unroll
                for (int rr = 0; rr < 4; rr++) {
                    int gi = mb * TM + wm + 16 * i + crow + rr;
                    if (gi < cnt)
                        pout[((size_t)(raws[i][rr] & 0xFFFF) * 2 + (raws[i][rr] >> 16)) * HD + n] =
                            (acc[i][j][rr] + b2v) * wgts[i][rr];
                }
        }
    } else {
        #pragma unroll
        for (int j = 0; j < 4; j++) {
            int n = nb * TN + wn + 16 * j + lr;
            float b2v = b2[e * HD + n];
            #pragma unroll
            for (int i = 0; i < 4; i++)
                #pragma unroll
                for (int rr = 0; rr < 4; rr++)
                    atomicAdd(&out[(size_t)(raws[i][rr] & 0xFFFF) * HD + n],
                              (acc[i][j][rr] + b2v) * wgts[i][rr]);
        }
    }
}

// combine: out[t] = pout[t][0] + pout[t][1]  (weights & biases already folded)
__global__ __launch_bounds__(256) void combine_kernel(
    const float* __restrict__ pout, float* __restrict__ out)
{
    int idx = blockIdx.x * 256 + threadIdx.x;          // TOK*HD/4 float4s
    int t = idx >> 7;                                  // 128 float4 per token
    int c4 = idx & 127;
    const float4* p = (const float4*)pout;
    float4 a = p[((size_t)t * 2 + 0) * 128 + c4];
    float4 b = p[((size_t)t * 2 + 1) * 128 + c4];
    float4 r; r.x = a.x + b.x; r.y = a.y + b.y; r.z = a.z + b.z; r.w = a.w + b.w;
    ((float4*)out)[idx] = r;
}

// ---------------- fused fallback (ws too small): full-unroll ----------------
#define BMT 64
#define FK  64
#define XS_LD 520
#define HS_LD 72

__global__ __launch_bounds__(256, 2) void ffn_fused_fallback(
    const unsigned short* __restrict__ xb,
    const unsigned short* __restrict__ W1t, const float* __restrict__ b1,
    const unsigned short* __restrict__ W2t, const float* __restrict__ b2,
    const int* __restrict__ seg_count, const int* __restrict__ seg_token,
    const float* __restrict__ seg_w, float* __restrict__ out)
{
    int bid = blockIdx.x;
    int e = bid & 7;
    int g = bid >> 3;
    int cnt = seg_count[e];
    int n0 = g * BMT;
    if (n0 >= cnt) return;
    int rows = min(BMT, cnt - n0);

    __shared__ unsigned short xs[BMT * XS_LD];
    __shared__ unsigned short hs[BMT * HS_LD];
    __shared__ int   tok_s[BMT];
    __shared__ float wgt_s[BMT];

    int tid = threadIdx.x;
    if (tid < BMT) {
        int idx = (tid < rows) ? (n0 + tid) : n0;
        tok_s[tid] = seg_token[e * TOK + idx] & 0xFFFF;
        wgt_s[tid] = (tid < rows) ? seg_w[e * TOK + idx] : 0.f;
    }
    __syncthreads();
    {
        int r = tid >> 2, q = tid & 3;
        const uint4* src = (const uint4*)(xb + (size_t)tok_s[r] * HD) + q * 16;
        uint4* dst = (uint4*)&xs[(size_t)r * XS_LD + q * 128];
        #pragma unroll
        for (int i = 0; i < 16; i++) dst[i] = src[i];
    }
    __syncthreads();

    int w = tid >> 6, l = tid & 63;
    int lr = l & 15, lk = (l >> 4) * 8, crow = (l >> 4) * 4;

    const unsigned short* w1e = W1t + (size_t)e * DFF * HD;
    const unsigned short* w2e = W2t + (size_t)e * HD * DFF;

    floatx4 acc2[4][8];
    #pragma unroll
    for (int i = 0; i < 4; i++)
        #pragma unroll
        for (int j = 0; j < 8; j++) acc2[i][j] = (floatx4){0.f, 0.f, 0.f, 0.f};

    for (int fc = 0; fc < DFF; fc += FK) {
        floatx4 acc1[4];
        #pragma unroll
        for (int t = 0; t < 4; t++) acc1[t] = (floatx4){0.f, 0.f, 0.f, 0.f};
        const unsigned short* w1c = w1e + (size_t)fc * HD;
        for (int ks = 0; ks < HD; ks += 32) {
            bf16x8 a = *(const bf16x8*)&xs[(16 * w + lr) * XS_LD + ks + lk];
            #pragma unroll
            for (int t = 0; t < 4; t++) {
                bf16x8 b = *(const bf16x8*)(w1c + (size_t)(16 * t + lr) * HD + ks + lk);
                acc1[t] = __builtin_amdgcn_mfma_f32_16x16x32_bf16(a, b, acc1[t], 0, 0, 0);
            }
        }
        __syncthreads();
        #pragma unroll
        for (int t = 0; t < 4; t++) {
            float b1v = b1[e * DFF + fc + 16 * t + lr];
            #pragma unroll
            for (int r = 0; r < 4; r++)
                hs[(16 * w + crow + r) * HS_LD + 16 * t + lr] = f2bf(gelu_exact(acc1[t][r] + b1v));
        }
        __syncthreads();
        #pragma unroll
        for (int ks = 0; ks < FK; ks += 32) {
            bf16x8 af[4];
            #pragma unroll
            for (int i = 0; i < 4; i++) af[i] = *(const bf16x8*)&hs[(16 * i + lr) * HS_LD + ks + lk];
            #pragma unroll
            for (int j = 0; j < 8; j++) {      // FULL unroll (rule #20)
                bf16x8 b = *(const bf16x8*)(w2e + (size_t)(128 * w + 16 * j + lr) * DFF + fc + ks + lk);
                #pragma unroll
                for (int i = 0; i < 4; i++)
                    acc2[i][j] = __builtin_amdgcn_mfma_f32_16x16x32_bf16(af[i], b, acc2[i][j], 0, 0, 0);
            }
        }
    }
    #pragma unroll
    for (int j = 0; j < 8; j++) {
        int n = 128 * w + 16 * j + lr;
        float b2v = b2[e * HD + n];
        #pragma unroll
        for (int i = 0; i < 4; i++)
            #pragma unroll
            for (int r = 0; r < 4; r++) {
                int m = 16 * i + crow + r;
                atomicAdd(&out[(size_t)tok_s[m] * HD + n], (acc2[i][j][r] + b2v) * wgt_s[m]);
            }
    }
}

// tiny finalize for fallback path
__global__ void finalize_kernel(const int* __restrict__ seg_count,
                                const float* __restrict__ probs_sum,
                                float* __restrict__ out_tail)
{
    int tid = threadIdx.x;
    if (tid < NE) out_tail[1 + tid] = (float)seg_count[tid];
    if (tid == 0) {
        float s = 0.f;
        #pragma unroll
        for (int e = 0; e < NE; e++) {
            float p = probs_sum[e] * (1.f / (float)TOK);
            s += p * p;
        }
        out_tail[0] = s * (float)NE;
    }
}

extern "C" void kernel_launch(void* const* d_in, const int* in_sizes, int n_in,
                              void* d_out, int out_size, void* d_ws, size_t ws_size,
                              hipStream_t stream)
{
    const float* x  = (const float*)d_in[0];
    const float* gW = (const float*)d_in[1];
    const float* gb = (const float*)d_in[2];
    const float* W1 = (const float*)d_in[3];
    const float* b1 = (const float*)d_in[4];
    const float* W2 = (const float*)d_in[5];
    const float* b2 = (const float*)d_in[6];
    float* out = (float*)d_out;

    char* ws = (char*)d_ws;
    int*   seg_count = (int*)ws;                          // 32 B
    float* probs_sum = (float*)(ws + 32);                 // 32 B
    int*   seg_token = (int*)(ws + 4096);                 // 256 KiB
    float* seg_w     = (float*)(ws + 4096 + (size_t)NE * TOK * 4);   // 256 KiB

    const size_t HBUF_BYTES = (size_t)17408 * DFF * 2;    // 71.3 MB

    // ---- fast layout: pout overlays xb+W1t (dead during gemm2) ----
    const size_t F_POUT = 0xA0000;                        // 655,360 (after seg arrays)
    const size_t F_XB   = (1u  << 20);                    // inside pout region
    const size_t F_W1T  = (9u  << 20);                    // inside pout region
    const size_t F_W2T  = F_POUT + (size_t)TOK * 2 * HD * 4;   // 655,360 + 32 MiB
    const size_t F_HBUF = F_W2T + ((size_t)NE * DFF * HD * 2); // + 16 MiB
    const size_t WS_FAST = F_HBUF + HBUF_BYTES;           // ~122.3 MB

    // ---- mid layout (atomic epilogue) ----
    const size_t M_XB   = (1u  << 20);
    const size_t M_W1T  = (16u << 20);
    const size_t M_W2T  = (32u << 20);
    const size_t M_HBUF = (48u << 20);
    const size_t WS_MID = M_HBUF + HBUF_BYTES;            // ~121.6 MB

    hipMemsetAsync(d_ws, 0, 64, stream);

    if (ws_size >= WS_FAST) {
        unsigned short* xb   = (unsigned short*)(ws + F_XB);
        unsigned short* W1t  = (unsigned short*)(ws + F_W1T);
        unsigned short* W2t  = (unsigned short*)(ws + F_W2T);
        unsigned short* hbuf = (unsigned short*)(ws + F_HBUF);
        float*          pout = (float*)(ws + F_POUT);

        // gate + W1 transpose only (2080 blocks); W2 transpose rides with gemm1
        prep_kernel<<<2080, 256, 0, stream>>>(x, gW, gb, W1, W2,
                                              seg_count, probs_sum, seg_token, seg_w,
                                              xb, W1t, W2t);
        gemm1_kernel<<<G1_GRID + 2048, 256, 0, stream>>>(
            xb, W1t, b1, seg_count, probs_sum, seg_token, hbuf,
            out + (size_t)TOK * HD, W2, W2t);
        gemm2_kernel<<<NE * (HD / TN) * 64, 256, 0, stream>>>(
            hbuf, W2t, b2, seg_count, seg_token, seg_w, pout, out, 1);
        combine_kernel<<<(TOK * HD / 4) / 256, 256, 0, stream>>>(pout, out);
    } else if (ws_size >= WS_MID) {
        unsigned short* xb   = (unsigned short*)(ws + M_XB);
        unsigned short* W1t  = (unsigned short*)(ws + M_W1T);
        unsigned short* W2t  = (unsigned short*)(ws + M_W2T);
        unsigned short* hbuf = (unsigned short*)(ws + M_HBUF);

        hipMemsetAsync(d_out, 0, (size_t)TOK * HD * sizeof(float), stream);
        prep_kernel<<<2080, 256, 0, stream>>>(x, gW, gb, W1, W2,
                                              seg_count, probs_sum, seg_token, seg_w,
                                              xb, W1t, W2t);
        gemm1_kernel<<<G1_GRID + 2048, 256, 0, stream>>>(
            xb, W1t, b1, seg_count, probs_sum, seg_token, hbuf,
            out + (size_t)TOK * HD, W2, W2t);
        gemm2_kernel<<<NE * (HD / TN) * 64, 256, 0, stream>>>(
            hbuf, W2t, b2, seg_count, seg_token, seg_w, (float*)ws, out, 0);
    } else {
        unsigned short* xb   = (unsigned short*)(ws + M_XB);
        unsigned short* W1t  = (unsigned short*)(ws + M_W1T);
        unsigned short* W2t  = (unsigned short*)(ws + M_W2T);

        hipMemsetAsync(d_out, 0, (size_t)TOK * HD * sizeof(float), stream);
        prep_kernel<<<4128, 256, 0, stream>>>(x, gW, gb, W1, W2,
                                              seg_count, probs_sum, seg_token, seg_w,
                                              xb, W1t, W2t);
        finalize_kernel<<<1, 64, 0, stream>>>(seg_count, probs_sum, out + (size_t)TOK * HD);
        ffn_fused_fallback<<<(TOK / BMT) * NE, 256, 0, stream>>>(
            xb, W1t, b1, W2t, b2, seg_count, seg_token, seg_w, out);
    }
}